// Round 14
// baseline (164.822 us; speedup 1.0000x reference)
//
#include <hip/hip_runtime.h>
#include <hip/hip_bf16.h>
#include <cstring>

// GraphSAGE 2-layer, CSR-gather formulation (no float atomics).
//   h1 = relu(x@Ws1 + mean_agg(x)@Wn1 + b1)
//   out = h1@Ws2 + mean_agg(h1)@Wn2 + b2
// mean_agg(h)@W == mean_agg(h@W): project first, then aggregate projected rows.
// CSR via fixed-capacity bucket sort; partition+gemm1 fused (no data dep).
// R14: gemm2 FUSED into gather64's epilogue -- after the butterfly reduce all
// 64 lanes hold the aggregation sums, so the wave computes relu'd h1 in
// registers and does the per-node [64]x[64x32] projection in-wave (W2 slices
// in 32 VGPRs/lane, h1 broadcast via ds_bpermute shuffles). h1 never hits
// global memory; the VALU work hides in the t1 gather latency shadow.
// t1 fp8 e4m3 (3.2 MB, L2-resident); selfo/t2 bf16; fp32 accumulation.
// R9 lesson: LDS float atomics for aggregation = 356 us disaster.
// R11/R13 lesson: the gathers are L2-hit LATENCY bound; byte- and
// instruction-rate reductions on that path are exhausted.

#define FEATS 64
#define CLS   16
#define EPT   16      // edges/thread in partition role (4096 edges/block)
#define CAP   5120    // bucket capacity; mean 4081 edges/bucket, 16 sigma margin

typedef unsigned short bf16_t;
typedef float floatx2 __attribute__((ext_vector_type(2)));

__device__ __forceinline__ float bfbits2f(unsigned lo16) {
    unsigned v = lo16 << 16;
    float f;
    __builtin_memcpy(&f, &v, 4);
    return f;
}
__device__ __forceinline__ bf16_t f2bf(float f) {
    unsigned u;
    __builtin_memcpy(&u, &f, 4);
    u = (u + 0x7FFFu + ((u >> 16) & 1u)) >> 16;   // round-to-nearest-even
    return (bf16_t)u;
}
__device__ __forceinline__ unsigned pack2(float a, float b) {
    return (unsigned)f2bf(a) | ((unsigned)f2bf(b) << 16);
}
// pack 4 f32 -> 4 fp8 e4m3 in one dword (HW cvt, RNE)
__device__ __forceinline__ unsigned pack4_fp8(float a, float b, float c, float d) {
    int q = __builtin_amdgcn_cvt_pk_fp8_f32(a, b, 0, false);
    q = __builtin_amdgcn_cvt_pk_fp8_f32(c, d, q, true);
    return (unsigned)q;
}

// ---------------- fused: partition (blocks [0,nbp)) + GEMM1 (blocks [nbp, nbp+nbg)) ----------------
__global__ __launch_bounds__(256) void fused_pg_kernel(
    const int* __restrict__ src, const int* __restrict__ dst,
    int* __restrict__ bucket_cnt, int* __restrict__ epart, int E,
    const float* __restrict__ x, const float* __restrict__ Ws,
    const float* __restrict__ Wn, bf16_t* __restrict__ selfo,
    unsigned char* __restrict__ t1, int N, int nbp)
{
    __shared__ float smem[16512];   // 66 KB: gemm1 Wc[8192]+xs[8320]; partition hist/base
    int t = threadIdx.x;

    if ((int)blockIdx.x < nbp) {
        // ---- partition role ----
        int* hist = (int*)smem;
        int* base = hist + 256;
        int e0 = blockIdx.x * (256 * EPT);
        hist[t] = 0;
        __syncthreads();
        int pk[EPT];
        int bk[EPT];
#pragma unroll
        for (int j = 0; j < EPT; ++j) {
            int e = e0 + j * 256 + t;
            if (e < E) {
                int d = dst[e];
                pk[j] = (src[e] << 8) | (d & 255);
                bk[j] = d >> 8;
                atomicAdd(&hist[bk[j]], 1);
            } else bk[j] = -1;
        }
        __syncthreads();
        int c = hist[t];
        if (c) base[t] = atomicAdd(&bucket_cnt[t], c);
        hist[t] = 0;
        __syncthreads();
#pragma unroll
        for (int j = 0; j < EPT; ++j) {
            if (bk[j] >= 0) {
                int r = atomicAdd(&hist[bk[j]], 1);
                epart[bk[j] * CAP + base[bk[j]] + r] = pk[j];
            }
        }
        return;
    }

    // ---- gemm1 role ----
    float* Wc = smem;           // 64*128
    float* xs = smem + 8192;    // 128*65
    int node0 = ((int)blockIdx.x - nbp) * 128;

    for (int idx = t; idx < 64 * 128; idx += 256) {
        int k = idx >> 7, c = idx & 127;
        Wc[idx] = (c < 64) ? Ws[k * 64 + c] : Wn[k * 64 + (c - 64)];
    }
    for (int idx = t; idx < 128 * 16; idx += 256) {
        int row = idx >> 4, c4 = idx & 15;
        int node = node0 + row;
        float4 v = (node < N) ? ((const float4*)(x + (size_t)node * 64))[c4]
                              : make_float4(0.f, 0.f, 0.f, 0.f);
        float* p = &xs[row * 65 + c4 * 4];
        p[0] = v.x; p[1] = v.y; p[2] = v.z; p[3] = v.w;
    }
    __syncthreads();

    int m = t & 31;
    int g = t >> 5;            // 8 col-groups of 16
    float acc[4][16];
#pragma unroll
    for (int j = 0; j < 4; ++j)
#pragma unroll
        for (int c = 0; c < 16; ++c) acc[j][c] = 0.f;

    for (int k = 0; k < 64; ++k) {
        float w[16];
        const float* wp = &Wc[k * 128 + g * 16];
#pragma unroll
        for (int c = 0; c < 16; ++c) w[c] = wp[c];
        float a0 = xs[m * 65 + k];
        float a1 = xs[(m + 32) * 65 + k];
        float a2 = xs[(m + 64) * 65 + k];
        float a3 = xs[(m + 96) * 65 + k];
#pragma unroll
        for (int c = 0; c < 16; ++c) {
            acc[0][c] += a0 * w[c];
            acc[1][c] += a1 * w[c];
            acc[2][c] += a2 * w[c];
            acc[3][c] += a3 * w[c];
        }
    }
#pragma unroll
    for (int j = 0; j < 4; ++j) {
        int node = node0 + m + 32 * j;
        if (node < N) {
            if (g < 4) {
                bf16_t* dstp = selfo + (size_t)node * 64 + g * 16;
                uint4 p0, p1;
                p0.x = pack2(acc[j][0],  acc[j][1]);  p0.y = pack2(acc[j][2],  acc[j][3]);
                p0.z = pack2(acc[j][4],  acc[j][5]);  p0.w = pack2(acc[j][6],  acc[j][7]);
                p1.x = pack2(acc[j][8],  acc[j][9]);  p1.y = pack2(acc[j][10], acc[j][11]);
                p1.z = pack2(acc[j][12], acc[j][13]); p1.w = pack2(acc[j][14], acc[j][15]);
                *(uint4*)(dstp) = p0;
                *(uint4*)(dstp + 8) = p1;
            } else {
                unsigned char* dstp = t1 + (size_t)node * 64 + (g - 4) * 16;
                uint4 q;
                q.x = pack4_fp8(acc[j][0],  acc[j][1],  acc[j][2],  acc[j][3]);
                q.y = pack4_fp8(acc[j][4],  acc[j][5],  acc[j][6],  acc[j][7]);
                q.z = pack4_fp8(acc[j][8],  acc[j][9],  acc[j][10], acc[j][11]);
                q.w = pack4_fp8(acc[j][12], acc[j][13], acc[j][14], acc[j][15]);
                *(uint4*)(dstp) = q;
            }
        }
    }
}

// ---------------- per-bucket CSR build, all bookkeeping in LDS (512 thr) ----------------
__global__ __launch_bounds__(512) void buildcsr_kernel(const int* __restrict__ epart,
                                                       const int* __restrict__ bucket_cnt,
                                                       int* __restrict__ row_start,
                                                       unsigned short* __restrict__ deg16,
                                                       int* __restrict__ csr, int N) {
    __shared__ int cnt[256];
    __shared__ int pref[256];
    __shared__ int s[256];
    int t = threadIdx.x;
    int b = blockIdx.x;
    int ebeg = b * CAP;
    int ecnt = bucket_cnt[b];
    if (t < 256) cnt[t] = 0;
    __syncthreads();
    for (int e = t; e < ecnt; e += 512)
        atomicAdd(&cnt[epart[ebeg + e] & 255], 1);
    __syncthreads();
    int v = 0;
    if (t < 256) { v = cnt[t]; s[t] = v; }
    __syncthreads();
    for (int off = 1; off < 256; off <<= 1) {
        int u = (t < 256 && t >= off) ? s[t - off] : 0;
        __syncthreads();
        if (t < 256) s[t] += u;
        __syncthreads();
    }
    if (t < 256) {
        pref[t] = s[t] - v;
        int node = b * 256 + t;
        if (node < N) {
            row_start[node] = ebeg + pref[t];
            deg16[node] = (unsigned short)v;
        }
        cnt[t] = 0;
    }
    __syncthreads();
    for (int e = t; e < ecnt; e += 512) {
        int pk = epart[ebeg + e];
        int ln = pk & 255;
        int r = atomicAdd(&cnt[ln], 1);
        csr[ebeg + pref[ln] + r] = pk >> 8;
    }
}

// ---------------- gather64+gemm2 fused ----------------
// one wave per node. Phase 1 (gather): lane = (eslot, cg) = 8 edge slots x 8
// col-groups, uint2 loads of fp8 rows; butterfly reduce leaves FULL sums in
// every lane (a[e] = col cg*8+e). Phase 2: all lanes build relu'd h1 fragment
// r[0..7] in registers; per-node projection out[c] = sum_k h1[k]*W2[k][c] with
// W2 slices preloaded in 32 VGPRs (c=lane&31, k-half h=lane>>5), h1 broadcast
// via __shfl (src lane 4h+(j>>3)), then shfl_xor(32) combines k-halves.
// Lanes 0..15 write out self-part f32; lanes 16..31 pack t2 bf16 pairs.
__global__ __launch_bounds__(256) void gather64g2_kernel(
    const int* __restrict__ csr, const int* __restrict__ row_start,
    const unsigned short* __restrict__ deg16,
    const unsigned char* __restrict__ t1, const bf16_t* __restrict__ selfo,
    const float* __restrict__ b1,
    const float* __restrict__ Ws2, const float* __restrict__ Wn2,
    float* __restrict__ outp, bf16_t* __restrict__ t2, int N)
{
    int wid = (blockIdx.x * 256 + threadIdx.x) >> 6;
    int lane = threadIdx.x & 63;
    int eslot = lane >> 3;       // 0..7
    int cg = lane & 7;           // cols [cg*8, cg*8+8)
    if (wid >= N) return;

    // W2 column-slice preload: c = lane&31, k-half h = lane>>5
    int c = lane & 31;
    int h = lane >> 5;
    float Wreg[32];
    {
        const float* Wbase = (c < 16) ? (Ws2 + c) : (Wn2 + (c - 16));
#pragma unroll
        for (int j = 0; j < 32; ++j)
            Wreg[j] = Wbase[(32 * h + j) * 16];
    }

    int beg = row_start[wid];
    int d = deg16[wid];
    float a[8];
#pragma unroll
    for (int e = 0; e < 8; ++e) a[e] = 0.f;
    int i = eslot;
    for (; i + 8 < d; i += 16) {
        int s0 = csr[beg + i];
        int s1 = csr[beg + i + 8];
        uint2 r0 = *(const uint2*)(t1 + (size_t)s0 * 64 + cg * 8);
        uint2 r1 = *(const uint2*)(t1 + (size_t)s1 * 64 + cg * 8);
        floatx2 p0 = __builtin_amdgcn_cvt_pk_f32_fp8((int)r0.x, false);
        floatx2 p1 = __builtin_amdgcn_cvt_pk_f32_fp8((int)r0.x, true);
        floatx2 p2 = __builtin_amdgcn_cvt_pk_f32_fp8((int)r0.y, false);
        floatx2 p3 = __builtin_amdgcn_cvt_pk_f32_fp8((int)r0.y, true);
        floatx2 q0 = __builtin_amdgcn_cvt_pk_f32_fp8((int)r1.x, false);
        floatx2 q1 = __builtin_amdgcn_cvt_pk_f32_fp8((int)r1.x, true);
        floatx2 q2 = __builtin_amdgcn_cvt_pk_f32_fp8((int)r1.y, false);
        floatx2 q3 = __builtin_amdgcn_cvt_pk_f32_fp8((int)r1.y, true);
        a[0] += p0.x + q0.x;  a[1] += p0.y + q0.y;
        a[2] += p1.x + q1.x;  a[3] += p1.y + q1.y;
        a[4] += p2.x + q2.x;  a[5] += p2.y + q2.y;
        a[6] += p3.x + q3.x;  a[7] += p3.y + q3.y;
    }
    if (i < d) {
        int s0 = csr[beg + i];
        uint2 r0 = *(const uint2*)(t1 + (size_t)s0 * 64 + cg * 8);
        floatx2 p0 = __builtin_amdgcn_cvt_pk_f32_fp8((int)r0.x, false);
        floatx2 p1 = __builtin_amdgcn_cvt_pk_f32_fp8((int)r0.x, true);
        floatx2 p2 = __builtin_amdgcn_cvt_pk_f32_fp8((int)r0.y, false);
        floatx2 p3 = __builtin_amdgcn_cvt_pk_f32_fp8((int)r0.y, true);
        a[0] += p0.x; a[1] += p0.y; a[2] += p1.x; a[3] += p1.y;
        a[4] += p2.x; a[5] += p2.y; a[6] += p3.x; a[7] += p3.y;
    }
    // butterfly: every lane ends with the full sum for its cg
#pragma unroll
    for (int e = 0; e < 8; ++e) {
        a[e] += __shfl_xor(a[e], 8);
        a[e] += __shfl_xor(a[e], 16);
        a[e] += __shfl_xor(a[e], 32);
    }

    // relu'd h1 fragment, all lanes (cols cg*8 + 0..7)
    float inv = 1.f / fmaxf((float)d, 1.f);
    uint4 su = *(const uint4*)(selfo + (size_t)wid * 64 + cg * 8);
    float4 b0 = *(const float4*)(b1 + cg * 8);
    float4 b4 = *(const float4*)(b1 + cg * 8 + 4);
    float r[8];
    r[0] = fmaxf(bfbits2f(su.x & 0xffff) + a[0] * inv + b0.x, 0.f);
    r[1] = fmaxf(bfbits2f(su.x >> 16)    + a[1] * inv + b0.y, 0.f);
    r[2] = fmaxf(bfbits2f(su.y & 0xffff) + a[2] * inv + b0.z, 0.f);
    r[3] = fmaxf(bfbits2f(su.y >> 16)    + a[3] * inv + b0.w, 0.f);
    r[4] = fmaxf(bfbits2f(su.z & 0xffff) + a[4] * inv + b4.x, 0.f);
    r[5] = fmaxf(bfbits2f(su.z >> 16)    + a[5] * inv + b4.y, 0.f);
    r[6] = fmaxf(bfbits2f(su.w & 0xffff) + a[6] * inv + b4.z, 0.f);
    r[7] = fmaxf(bfbits2f(su.w >> 16)    + a[7] * inv + b4.w, 0.f);

    // in-wave gemm2: out[c] = sum_k h1[k] * W2[k][c]
    float acc = 0.f;
    int srcbase = h * 4;
#pragma unroll
    for (int j = 0; j < 32; ++j) {
        float v = __shfl(r[j & 7], srcbase + (j >> 3));
        acc += v * Wreg[j];
    }
    acc += __shfl_xor(acc, 32);          // combine k-halves; lanes 0..31 valid
    float partner = __shfl_xor(acc, 1);
    if (lane < 16) {
        outp[(size_t)wid * 16 + lane] = acc;           // self-part f32
    } else if (lane < 32 && !(lane & 1)) {
        unsigned pk = pack2(acc, partner);             // t2 bf16 pair
        *(unsigned*)(t2 + (size_t)wid * 16 + (lane - 16)) = pk;
    }
}

// ---------------- gather16: out += (sum t2[src])/deg + b2 ----------------
// one wave per node; lane = (eslot, cg): 16 edge slots x 4 col-groups.
__global__ __launch_bounds__(256) void gather16_kernel(
    const int* __restrict__ csr, const int* __restrict__ row_start,
    const unsigned short* __restrict__ deg16,
    const bf16_t* __restrict__ t2,
    float* __restrict__ outp, const float* __restrict__ b2, int N)
{
    int wid = (blockIdx.x * 256 + threadIdx.x) >> 6;
    int lane = threadIdx.x & 63;
    int eslot = lane >> 2;       // 0..15
    int cg = lane & 3;           // cols [cg*4, cg*4+4)
    if (wid >= N) return;
    int beg = row_start[wid];
    int d = deg16[wid];
    float a0 = 0.f, a1 = 0.f, a2 = 0.f, a3 = 0.f;
    for (int i = eslot; i < d; i += 16) {
        int s0 = csr[beg + i];
        uint2 u = *(const uint2*)(t2 + (size_t)s0 * 16 + cg * 4);
        a0 += bfbits2f(u.x & 0xffff);
        a1 += bfbits2f(u.x >> 16);
        a2 += bfbits2f(u.y & 0xffff);
        a3 += bfbits2f(u.y >> 16);
    }
    a0 += __shfl_xor(a0, 4); a1 += __shfl_xor(a1, 4);
    a2 += __shfl_xor(a2, 4); a3 += __shfl_xor(a3, 4);
    a0 += __shfl_xor(a0, 8); a1 += __shfl_xor(a1, 8);
    a2 += __shfl_xor(a2, 8); a3 += __shfl_xor(a3, 8);
    a0 += __shfl_xor(a0, 16); a1 += __shfl_xor(a1, 16);
    a2 += __shfl_xor(a2, 16); a3 += __shfl_xor(a3, 16);
    a0 += __shfl_xor(a0, 32); a1 += __shfl_xor(a1, 32);
    a2 += __shfl_xor(a2, 32); a3 += __shfl_xor(a3, 32);
    if (eslot == 0) {
        float inv = 1.f / fmaxf((float)d, 1.f);
        size_t o = (size_t)wid * 16 + cg * 4;
        float4 bb = *(const float4*)(b2 + cg * 4);
        float4 ov = *(const float4*)(outp + o);
        ov.x += a0 * inv + bb.x;
        ov.y += a1 * inv + bb.y;
        ov.z += a2 * inv + bb.z;
        ov.w += a3 * inv + bb.w;
        *(float4*)(outp + o) = ov;
    }
}

extern "C" void kernel_launch(void* const* d_in, const int* in_sizes, int n_in,
                              void* d_out, int out_size, void* d_ws, size_t ws_size,
                              hipStream_t stream) {
    const float* x   = (const float*)d_in[0];
    const int*   src = (const int*)d_in[1];
    const int*   dst = (const int*)d_in[2];
    const float* Ws1 = (const float*)d_in[3];
    const float* Wn1 = (const float*)d_in[4];
    const float* b1  = (const float*)d_in[5];
    const float* Ws2 = (const float*)d_in[6];
    const float* Wn2 = (const float*)d_in[7];
    const float* b2  = (const float*)d_in[8];
    float* outp = (float*)d_out;

    const int N = in_sizes[0] / FEATS;   // 50000
    const int E = in_sizes[1];           // 800000
    const int B = (N + 255) / 256;       // buckets (196) — must be <= 256
    const int NBP = (E + 256 * EPT - 1) / (256 * EPT);   // partition blocks (196)
    const int NBG = (N + 127) / 128;                     // gemm1 blocks (391)

    // workspace: bucket_cnt[256] | epart[B*CAP] | csr[B*CAP] | row_start[N] |
    // deg16[N] u16 | selfo bf16[N*64] | t1 fp8[N*64] | t2 bf16[N*16]
    char* p = (char*)d_ws;
    auto align16 = [](char* q) { return (char*)(((size_t)q + 15) & ~(size_t)15); };
    int* bucket_cnt    = (int*)p;                  p = (char*)(bucket_cnt + 256);
    int* epart         = (int*)p;                  p = (char*)(epart + (size_t)B * CAP);
    int* csr           = (int*)p;                  p = (char*)(csr + (size_t)B * CAP);
    int* row_start     = (int*)align16(p);         p = (char*)(row_start + N);
    unsigned short* deg16 = (unsigned short*)align16(p); p = (char*)(deg16 + N);
    bf16_t* selfo      = (bf16_t*)align16(p);      p = (char*)(selfo + (size_t)N * 64);
    unsigned char* t1  = (unsigned char*)align16(p); p = (char*)(t1 + (size_t)N * 64);
    bf16_t* t2         = (bf16_t*)align16(p);

    hipMemsetAsync(bucket_cnt, 0, 256 * sizeof(int), stream);

    fused_pg_kernel<<<NBP + NBG, 256, 0, stream>>>(
        src, dst, bucket_cnt, epart, E, x, Ws1, Wn1, selfo, t1, N, NBP);
    buildcsr_kernel<<<B, 512, 0, stream>>>(epart, bucket_cnt, row_start, deg16, csr, N);

    gather64g2_kernel<<<((size_t)N * 64 + 255) / 256, 256, 0, stream>>>(
        csr, row_start, deg16, t1, selfo, b1, Ws2, Wn2, outp, t2, N);
    gather16_kernel<<<((size_t)N * 64 + 255) / 256, 256, 0, stream>>>(
        csr, row_start, deg16, t2, outp, b2, N);
}

// Round 15
// 159.860 us; speedup vs baseline: 1.0310x; 1.0310x over previous
//
#include <hip/hip_runtime.h>
#include <hip/hip_bf16.h>
#include <cstring>

// GraphSAGE 2-layer, CSR-gather formulation (no float atomics).
//   h1 = relu(x@Ws1 + mean_agg(x)@Wn1 + b1)
//   out = h1@Ws2 + mean_agg(h1)@Wn2 + b2
// mean_agg(h)@W == mean_agg(h@W): project first, then aggregate projected rows.
// CSR via fixed-capacity bucket sort; partition+gemm1 fused (no data dep).
// t1 fp8 e4m3 (3.2 MB, L2-resident gather table); selfo/t2 bf16; fp32 acc.
// BEST-MEASURED structure (R12, 162.07 us). Closed experiment families:
//  R9:  LDS float-atomic aggregation -> 356 us disaster (serialized RMW).
//  R11: gather byte-shrink (fp8) -> small win; gathers are L2-hit LATENCY bound.
//  R13: wide-load instr-rate reduction -> neutral (confirms latency-bound).
//  R14: per-node in-wave gemm2 fusion -> regression (destroys W-tile reuse;
//       per-node operand movement > the 7 us tile GEMM it replaced).

#define FEATS 64
#define CLS   16
#define EPT   16      // edges/thread in partition role (4096 edges/block)
#define CAP   5120    // bucket capacity; mean 4081 edges/bucket, 16 sigma margin

typedef unsigned short bf16_t;
typedef float floatx2 __attribute__((ext_vector_type(2)));

__device__ __forceinline__ float bfbits2f(unsigned lo16) {
    unsigned v = lo16 << 16;
    float f;
    __builtin_memcpy(&f, &v, 4);
    return f;
}
__device__ __forceinline__ bf16_t f2bf(float f) {
    unsigned u;
    __builtin_memcpy(&u, &f, 4);
    u = (u + 0x7FFFu + ((u >> 16) & 1u)) >> 16;   // round-to-nearest-even
    return (bf16_t)u;
}
__device__ __forceinline__ unsigned pack2(float a, float b) {
    return (unsigned)f2bf(a) | ((unsigned)f2bf(b) << 16);
}
// pack 4 f32 -> 4 fp8 e4m3 in one dword (HW cvt, RNE)
__device__ __forceinline__ unsigned pack4_fp8(float a, float b, float c, float d) {
    int q = __builtin_amdgcn_cvt_pk_fp8_f32(a, b, 0, false);
    q = __builtin_amdgcn_cvt_pk_fp8_f32(c, d, q, true);
    return (unsigned)q;
}

// ---------------- fused: partition (blocks [0,nbp)) + GEMM1 (blocks [nbp, nbp+nbg)) ----------------
__global__ __launch_bounds__(256) void fused_pg_kernel(
    const int* __restrict__ src, const int* __restrict__ dst,
    int* __restrict__ bucket_cnt, int* __restrict__ epart, int E,
    const float* __restrict__ x, const float* __restrict__ Ws,
    const float* __restrict__ Wn, bf16_t* __restrict__ selfo,
    unsigned char* __restrict__ t1, int N, int nbp)
{
    __shared__ float smem[16512];   // 66 KB: gemm1 Wc[8192]+xs[8320]; partition hist/base
    int t = threadIdx.x;

    if ((int)blockIdx.x < nbp) {
        // ---- partition role ----
        int* hist = (int*)smem;
        int* base = hist + 256;
        int e0 = blockIdx.x * (256 * EPT);
        hist[t] = 0;
        __syncthreads();
        int pk[EPT];
        int bk[EPT];
#pragma unroll
        for (int j = 0; j < EPT; ++j) {
            int e = e0 + j * 256 + t;
            if (e < E) {
                int d = dst[e];
                pk[j] = (src[e] << 8) | (d & 255);
                bk[j] = d >> 8;
                atomicAdd(&hist[bk[j]], 1);
            } else bk[j] = -1;
        }
        __syncthreads();
        int c = hist[t];
        if (c) base[t] = atomicAdd(&bucket_cnt[t], c);
        hist[t] = 0;
        __syncthreads();
#pragma unroll
        for (int j = 0; j < EPT; ++j) {
            if (bk[j] >= 0) {
                int r = atomicAdd(&hist[bk[j]], 1);
                epart[bk[j] * CAP + base[bk[j]] + r] = pk[j];
            }
        }
        return;
    }

    // ---- gemm1 role ----
    float* Wc = smem;           // 64*128
    float* xs = smem + 8192;    // 128*65
    int node0 = ((int)blockIdx.x - nbp) * 128;

    for (int idx = t; idx < 64 * 128; idx += 256) {
        int k = idx >> 7, c = idx & 127;
        Wc[idx] = (c < 64) ? Ws[k * 64 + c] : Wn[k * 64 + (c - 64)];
    }
    for (int idx = t; idx < 128 * 16; idx += 256) {
        int row = idx >> 4, c4 = idx & 15;
        int node = node0 + row;
        float4 v = (node < N) ? ((const float4*)(x + (size_t)node * 64))[c4]
                              : make_float4(0.f, 0.f, 0.f, 0.f);
        float* p = &xs[row * 65 + c4 * 4];
        p[0] = v.x; p[1] = v.y; p[2] = v.z; p[3] = v.w;
    }
    __syncthreads();

    int m = t & 31;
    int g = t >> 5;            // 8 col-groups of 16
    float acc[4][16];
#pragma unroll
    for (int j = 0; j < 4; ++j)
#pragma unroll
        for (int c = 0; c < 16; ++c) acc[j][c] = 0.f;

    for (int k = 0; k < 64; ++k) {
        float w[16];
        const float* wp = &Wc[k * 128 + g * 16];
#pragma unroll
        for (int c = 0; c < 16; ++c) w[c] = wp[c];
        float a0 = xs[m * 65 + k];
        float a1 = xs[(m + 32) * 65 + k];
        float a2 = xs[(m + 64) * 65 + k];
        float a3 = xs[(m + 96) * 65 + k];
#pragma unroll
        for (int c = 0; c < 16; ++c) {
            acc[0][c] += a0 * w[c];
            acc[1][c] += a1 * w[c];
            acc[2][c] += a2 * w[c];
            acc[3][c] += a3 * w[c];
        }
    }
#pragma unroll
    for (int j = 0; j < 4; ++j) {
        int node = node0 + m + 32 * j;
        if (node < N) {
            if (g < 4) {
                bf16_t* dstp = selfo + (size_t)node * 64 + g * 16;
                uint4 p0, p1;
                p0.x = pack2(acc[j][0],  acc[j][1]);  p0.y = pack2(acc[j][2],  acc[j][3]);
                p0.z = pack2(acc[j][4],  acc[j][5]);  p0.w = pack2(acc[j][6],  acc[j][7]);
                p1.x = pack2(acc[j][8],  acc[j][9]);  p1.y = pack2(acc[j][10], acc[j][11]);
                p1.z = pack2(acc[j][12], acc[j][13]); p1.w = pack2(acc[j][14], acc[j][15]);
                *(uint4*)(dstp) = p0;
                *(uint4*)(dstp + 8) = p1;
            } else {
                unsigned char* dstp = t1 + (size_t)node * 64 + (g - 4) * 16;
                uint4 q;
                q.x = pack4_fp8(acc[j][0],  acc[j][1],  acc[j][2],  acc[j][3]);
                q.y = pack4_fp8(acc[j][4],  acc[j][5],  acc[j][6],  acc[j][7]);
                q.z = pack4_fp8(acc[j][8],  acc[j][9],  acc[j][10], acc[j][11]);
                q.w = pack4_fp8(acc[j][12], acc[j][13], acc[j][14], acc[j][15]);
                *(uint4*)(dstp) = q;
            }
        }
    }
}

// ---------------- per-bucket CSR build, all bookkeeping in LDS ----------------
__global__ __launch_bounds__(256) void buildcsr_kernel(const int* __restrict__ epart,
                                                       const int* __restrict__ bucket_cnt,
                                                       int* __restrict__ row_start,
                                                       unsigned short* __restrict__ deg16,
                                                       int* __restrict__ csr, int N) {
    __shared__ int cnt[256];
    __shared__ int pref[256];
    __shared__ int s[256];
    int t = threadIdx.x;
    int b = blockIdx.x;
    int ebeg = b * CAP;
    int ecnt = bucket_cnt[b];
    cnt[t] = 0;
    __syncthreads();
    for (int e = t; e < ecnt; e += 256)
        atomicAdd(&cnt[epart[ebeg + e] & 255], 1);
    __syncthreads();
    int v = cnt[t];
    s[t] = v;
    __syncthreads();
    for (int off = 1; off < 256; off <<= 1) {
        int u = (t >= off) ? s[t - off] : 0;
        __syncthreads();
        s[t] += u;
        __syncthreads();
    }
    pref[t] = s[t] - v;
    int node = b * 256 + t;
    if (node < N) {
        row_start[node] = ebeg + pref[t];
        deg16[node] = (unsigned short)v;
    }
    cnt[t] = 0;
    __syncthreads();
    for (int e = t; e < ecnt; e += 256) {
        int pk = epart[ebeg + e];
        int ln = pk & 255;
        int r = atomicAdd(&cnt[ln], 1);
        csr[ebeg + pref[ln] + r] = pk >> 8;
    }
}

// ---------------- gather64: h1 = relu(selfo + (sum t1[src])/deg + b1) ----------------
// one wave per node; lane = (eslot, cg): 4 edge slots x 16 col-groups (dword = 4 fp8).
__global__ __launch_bounds__(256) void gather64_kernel(
    const int* __restrict__ csr, const int* __restrict__ row_start,
    const unsigned short* __restrict__ deg16,
    const unsigned char* __restrict__ t1, const bf16_t* __restrict__ selfo,
    bf16_t* __restrict__ h1, const float* __restrict__ b1, int N)
{
    int wid = (blockIdx.x * 256 + threadIdx.x) >> 6;
    int lane = threadIdx.x & 63;
    int eslot = lane >> 4;       // 0..3
    int cg = lane & 15;          // cols [cg*4, cg*4+4)
    if (wid >= N) return;
    int beg = row_start[wid];
    int d = deg16[wid];
    float ax = 0.f, ay = 0.f, az = 0.f, aw = 0.f;
    int i = eslot;
    for (; i + 12 < d; i += 16) {
        int s0 = csr[beg + i];
        int s1 = csr[beg + i + 4];
        int s2 = csr[beg + i + 8];
        int s3 = csr[beg + i + 12];
        unsigned r0 = *(const unsigned*)(t1 + (size_t)s0 * 64 + cg * 4);
        unsigned r1 = *(const unsigned*)(t1 + (size_t)s1 * 64 + cg * 4);
        unsigned r2 = *(const unsigned*)(t1 + (size_t)s2 * 64 + cg * 4);
        unsigned r3 = *(const unsigned*)(t1 + (size_t)s3 * 64 + cg * 4);
        floatx2 p0 = __builtin_amdgcn_cvt_pk_f32_fp8((int)r0, false);
        floatx2 q0 = __builtin_amdgcn_cvt_pk_f32_fp8((int)r0, true);
        floatx2 p1 = __builtin_amdgcn_cvt_pk_f32_fp8((int)r1, false);
        floatx2 q1 = __builtin_amdgcn_cvt_pk_f32_fp8((int)r1, true);
        floatx2 p2 = __builtin_amdgcn_cvt_pk_f32_fp8((int)r2, false);
        floatx2 q2 = __builtin_amdgcn_cvt_pk_f32_fp8((int)r2, true);
        floatx2 p3 = __builtin_amdgcn_cvt_pk_f32_fp8((int)r3, false);
        floatx2 q3 = __builtin_amdgcn_cvt_pk_f32_fp8((int)r3, true);
        ax += p0.x + p1.x + p2.x + p3.x;
        ay += p0.y + p1.y + p2.y + p3.y;
        az += q0.x + q1.x + q2.x + q3.x;
        aw += q0.y + q1.y + q2.y + q3.y;
    }
    for (; i < d; i += 4) {
        int s0 = csr[beg + i];
        unsigned r0 = *(const unsigned*)(t1 + (size_t)s0 * 64 + cg * 4);
        floatx2 p0 = __builtin_amdgcn_cvt_pk_f32_fp8((int)r0, false);
        floatx2 q0 = __builtin_amdgcn_cvt_pk_f32_fp8((int)r0, true);
        ax += p0.x; ay += p0.y; az += q0.x; aw += q0.y;
    }
    ax += __shfl_xor(ax, 16); ay += __shfl_xor(ay, 16);
    az += __shfl_xor(az, 16); aw += __shfl_xor(aw, 16);
    ax += __shfl_xor(ax, 32); ay += __shfl_xor(ay, 32);
    az += __shfl_xor(az, 32); aw += __shfl_xor(aw, 32);
    if (eslot == 0) {
        float inv = 1.f / fmaxf((float)d, 1.f);
        size_t o = (size_t)wid * 64 + cg * 4;
        uint2 su = *(const uint2*)(selfo + o);
        float4 bb = *(const float4*)(b1 + cg * 4);
        float rx = fmaxf(bfbits2f(su.x & 0xffff) + ax * inv + bb.x, 0.f);
        float ry = fmaxf(bfbits2f(su.x >> 16)    + ay * inv + bb.y, 0.f);
        float rz = fmaxf(bfbits2f(su.y & 0xffff) + az * inv + bb.z, 0.f);
        float rw = fmaxf(bfbits2f(su.y >> 16)    + aw * inv + bb.w, 0.f);
        uint2 pk;
        pk.x = pack2(rx, ry);
        pk.y = pack2(rz, rw);
        *(uint2*)(h1 + o) = pk;
    }
}

// ---------------- GEMM2: h1(bf16) [N,64] x [64,32] -> out(self) [N,16] f32, t2 [N,16] bf16 ----------------
__global__ __launch_bounds__(256) void gemm2_kernel(
    const bf16_t* __restrict__ h1, const float* __restrict__ Ws,
    const float* __restrict__ Wn, float* __restrict__ outp,
    bf16_t* __restrict__ t2, int N)
{
    __shared__ float Wc[64 * 32];    // 8 KB
    __shared__ float xs[128 * 65];   // 33.3 KB
    int t = threadIdx.x;
    int node0 = blockIdx.x * 128;

    for (int idx = t; idx < 64 * 32; idx += 256) {
        int k = idx >> 5, c = idx & 31;
        Wc[idx] = (c < 16) ? Ws[k * 16 + c] : Wn[k * 16 + (c - 16)];
    }
    for (int idx = t; idx < 128 * 8; idx += 256) {
        int row = idx >> 3, c8 = idx & 7;
        int node = node0 + row;
        float* p = &xs[row * 65 + c8 * 8];
        if (node < N) {
            uint4 u = *(const uint4*)(h1 + (size_t)node * 64 + c8 * 8);
            p[0] = bfbits2f(u.x & 0xffff); p[1] = bfbits2f(u.x >> 16);
            p[2] = bfbits2f(u.y & 0xffff); p[3] = bfbits2f(u.y >> 16);
            p[4] = bfbits2f(u.z & 0xffff); p[5] = bfbits2f(u.z >> 16);
            p[6] = bfbits2f(u.w & 0xffff); p[7] = bfbits2f(u.w >> 16);
        } else {
            for (int qq = 0; qq < 8; ++qq) p[qq] = 0.f;
        }
    }
    __syncthreads();

    int m = t & 31;
    int g = t >> 5;            // 8 col-groups of 4
    float acc[4][4];
#pragma unroll
    for (int j = 0; j < 4; ++j)
#pragma unroll
        for (int c = 0; c < 4; ++c) acc[j][c] = 0.f;

    for (int k = 0; k < 64; ++k) {
        float w[4];
        const float* wp = &Wc[k * 32 + g * 4];
#pragma unroll
        for (int c = 0; c < 4; ++c) w[c] = wp[c];
        float a0 = xs[m * 65 + k];
        float a1 = xs[(m + 32) * 65 + k];
        float a2 = xs[(m + 64) * 65 + k];
        float a3 = xs[(m + 96) * 65 + k];
#pragma unroll
        for (int c = 0; c < 4; ++c) {
            acc[0][c] += a0 * w[c];
            acc[1][c] += a1 * w[c];
            acc[2][c] += a2 * w[c];
            acc[3][c] += a3 * w[c];
        }
    }
#pragma unroll
    for (int j = 0; j < 4; ++j) {
        int node = node0 + m + 32 * j;
        if (node < N) {
            if (g < 4) {
                *(float4*)(outp + (size_t)node * 16 + g * 4) =
                    make_float4(acc[j][0], acc[j][1], acc[j][2], acc[j][3]);
            } else {
                uint2 pk;
                pk.x = pack2(acc[j][0], acc[j][1]);
                pk.y = pack2(acc[j][2], acc[j][3]);
                *(uint2*)(t2 + (size_t)node * 16 + (g - 4) * 4) = pk;
            }
        }
    }
}

// ---------------- gather16: out += (sum t2[src])/deg + b2 ----------------
// 8 threads per node, each handles 2 cols (uint loads), 4x unroll.
__global__ __launch_bounds__(256) void gather16_kernel(
    const int* __restrict__ csr, const int* __restrict__ row_start,
    const unsigned short* __restrict__ deg16,
    const bf16_t* __restrict__ t2,
    float* __restrict__ outp, const float* __restrict__ b2, int N)
{
    int gt = blockIdx.x * 256 + threadIdx.x;
    int node = gt >> 3;
    int c2 = gt & 7;             // cols [c2*2, c2*2+2)
    if (node >= N) return;
    int beg = row_start[node];
    int d = deg16[node];
    int end = beg + d;
    float a0 = 0.f, a1 = 0.f;
    int i = beg;
    for (; i + 4 <= end; i += 4) {
        int s0 = csr[i], s1 = csr[i + 1], s2 = csr[i + 2], s3 = csr[i + 3];
        unsigned u0 = *(const unsigned*)(t2 + (size_t)s0 * 16 + c2 * 2);
        unsigned u1 = *(const unsigned*)(t2 + (size_t)s1 * 16 + c2 * 2);
        unsigned u2 = *(const unsigned*)(t2 + (size_t)s2 * 16 + c2 * 2);
        unsigned u3 = *(const unsigned*)(t2 + (size_t)s3 * 16 + c2 * 2);
        a0 += bfbits2f(u0 & 0xffff) + bfbits2f(u1 & 0xffff)
            + bfbits2f(u2 & 0xffff) + bfbits2f(u3 & 0xffff);
        a1 += bfbits2f(u0 >> 16) + bfbits2f(u1 >> 16)
            + bfbits2f(u2 >> 16) + bfbits2f(u3 >> 16);
    }
    for (; i < end; ++i) {
        int s = csr[i];
        unsigned u = *(const unsigned*)(t2 + (size_t)s * 16 + c2 * 2);
        a0 += bfbits2f(u & 0xffff);
        a1 += bfbits2f(u >> 16);
    }
    float inv = 1.f / fmaxf((float)d, 1.f);
    size_t o = (size_t)node * 16 + c2 * 2;
    outp[o]     += a0 * inv + b2[c2 * 2];
    outp[o + 1] += a1 * inv + b2[c2 * 2 + 1];
}

extern "C" void kernel_launch(void* const* d_in, const int* in_sizes, int n_in,
                              void* d_out, int out_size, void* d_ws, size_t ws_size,
                              hipStream_t stream) {
    const float* x   = (const float*)d_in[0];
    const int*   src = (const int*)d_in[1];
    const int*   dst = (const int*)d_in[2];
    const float* Ws1 = (const float*)d_in[3];
    const float* Wn1 = (const float*)d_in[4];
    const float* b1  = (const float*)d_in[5];
    const float* Ws2 = (const float*)d_in[6];
    const float* Wn2 = (const float*)d_in[7];
    const float* b2  = (const float*)d_in[8];
    float* outp = (float*)d_out;

    const int N = in_sizes[0] / FEATS;   // 50000
    const int E = in_sizes[1];           // 800000
    const int B = (N + 255) / 256;       // buckets (196) — must be <= 256
    const int NBP = (E + 256 * EPT - 1) / (256 * EPT);   // partition blocks (196)
    const int NBG = (N + 127) / 128;                     // gemm1 blocks (391)

    // workspace: bucket_cnt[256] | epart[B*CAP] | csr[B*CAP] | row_start[N] |
    // deg16[N] u16 | selfo bf16[N*64] | t1 fp8[N*64] | h1 bf16[N*64] | t2 bf16[N*16]
    char* p = (char*)d_ws;
    auto align16 = [](char* q) { return (char*)(((size_t)q + 15) & ~(size_t)15); };
    int* bucket_cnt    = (int*)p;                  p = (char*)(bucket_cnt + 256);
    int* epart         = (int*)p;                  p = (char*)(epart + (size_t)B * CAP);
    int* csr           = (int*)p;                  p = (char*)(csr + (size_t)B * CAP);
    int* row_start     = (int*)align16(p);         p = (char*)(row_start + N);
    unsigned short* deg16 = (unsigned short*)align16(p); p = (char*)(deg16 + N);
    bf16_t* selfo      = (bf16_t*)align16(p);      p = (char*)(selfo + (size_t)N * 64);
    unsigned char* t1  = (unsigned char*)align16(p); p = (char*)(t1 + (size_t)N * 64);
    bf16_t* h1         = (bf16_t*)align16(p);      p = (char*)(h1 + (size_t)N * 64);
    bf16_t* t2         = (bf16_t*)align16(p);

    hipMemsetAsync(bucket_cnt, 0, 256 * sizeof(int), stream);

    fused_pg_kernel<<<NBP + NBG, 256, 0, stream>>>(
        src, dst, bucket_cnt, epart, E, x, Ws1, Wn1, selfo, t1, N, NBP);
    buildcsr_kernel<<<B, 256, 0, stream>>>(epart, bucket_cnt, row_start, deg16, csr, N);

    gather64_kernel<<<((size_t)N * 64 + 255) / 256, 256, 0, stream>>>(
        csr, row_start, deg16, t1, selfo, h1, b1, N);
    gemm2_kernel<<<(N + 127) / 128, 256, 0, stream>>>(h1, Ws2, Wn2, outp, t2, N);
    gather16_kernel<<<((size_t)N * 8 + 255) / 256, 256, 0, stream>>>(
        csr, row_start, deg16, t2, outp, b2, N);
}